// Round 2
// baseline (187.350 us; speedup 1.0000x reference)
//
#include <hip/hip_runtime.h>
#include <math.h>

#define SEQ_L 2048
#define DM 1024
#define NH 16
#define HD 64
#define NB 2
#define KD 1024   // GEMM K
#define ND 1024   // GEMM N

typedef __bf16 bf16;
typedef __bf16 bf16x8 __attribute__((ext_vector_type(8)));
typedef __bf16 bf16x4 __attribute__((ext_vector_type(4)));
typedef __bf16 bf16x2 __attribute__((ext_vector_type(2)));
typedef float f32x4 __attribute__((ext_vector_type(4)));

// ---------------- jax threefry2x32, key = (0, 42); partitionable random_bits ----------------
__device__ inline uint32_t rotl32(uint32_t v, int n) { return (v << n) | (v >> (32 - n)); }

__device__ inline void threefry(uint32_t x0, uint32_t x1, uint32_t* o0, uint32_t* o1) {
  const uint32_t ks0 = 0u, ks1 = 42u, ks2 = 0u ^ 42u ^ 0x1BD11BDAu;
  x0 += ks0; x1 += ks1;
#define TF_R(rr) { x0 += x1; x1 = rotl32(x1, rr); x1 ^= x0; }
  TF_R(13) TF_R(15) TF_R(26) TF_R(6)
  x0 += ks1; x1 += ks2 + 1u;
  TF_R(17) TF_R(29) TF_R(16) TF_R(24)
  x0 += ks2; x1 += ks0 + 2u;
  TF_R(13) TF_R(15) TF_R(26) TF_R(6)
  x0 += ks0; x1 += ks1 + 3u;
  TF_R(17) TF_R(29) TF_R(16) TF_R(24)
  x0 += ks1; x1 += ks2 + 4u;
  TF_R(13) TF_R(15) TF_R(26) TF_R(6)
  x0 += ks2; x1 += ks0 + 5u;
#undef TF_R
  *o0 = x0; *o1 = x1;
}

// jax_threefry_partitionable=True: counter (hi=0, lo=flat_idx), bits = o0 ^ o1.
__device__ inline int rand_col(int i, int s) {
  uint32_t o0, o1;
  threefry(0u, (uint32_t)(2 * i + s), &o0, &o1);
  uint32_t bits = o0 ^ o1;
  float u = __uint_as_float((bits >> 9) | 0x3f800000u) - 1.0f;
  return (int)floorf(u * (float)(i + 1));
}

// ---------------- prep: conversions + ctab + rope cos/sin table ----------------
__global__ void prep_kernel(const float* __restrict__ x,
                            const float* __restrict__ w0, const float* __restrict__ w1,
                            const float* __restrict__ w2, const float* __restrict__ w3,
                            const float* __restrict__ freqs,
                            bf16* __restrict__ xb,
                            bf16* __restrict__ o0, bf16* __restrict__ o1,
                            bf16* __restrict__ o2, bf16* __restrict__ o3,
                            int* __restrict__ ctab, float2* __restrict__ rtab) {
  const int bx = blockIdx.x;
  const int t = threadIdx.x;
  if (bx < 8192) {
    const float* src;
    bf16* dst;
    int idx;
    if (bx < 4096) { src = x; dst = xb; idx = bx * 256 + t; }
    else {
      int widx = bx - 4096;
      int wsel = widx >> 10;
      switch (wsel) {
        case 0: src = w0; dst = o0; break;
        case 1: src = w1; dst = o1; break;
        case 2: src = w2; dst = o2; break;
        default: src = w3; dst = o3; break;
      }
      idx = (widx & 1023) * 256 + t;
    }
    float4 vv = ((const float4*)src)[idx];
    bf16x4 ov;
    ov[0] = (bf16)vv.x; ov[1] = (bf16)vv.y; ov[2] = (bf16)vv.z; ov[3] = (bf16)vv.w;
    *(bf16x4*)(dst + (size_t)idx * 4) = ov;
    return;
  }
  if (bx < 8200) {
    const int i = (bx - 8192) * 256 + t;    // 0..2047
    int cols[11]; int nc = 0;
    if (i >= 1) {
      int lo = i - 7; if (lo < 0) lo = 0;
      for (int j = lo; j <= i; ++j) cols[nc++] = j;
      if (lo > 0) cols[nc++] = 0;
#pragma unroll
      for (int s = 0; s < 2; ++s) {
        int rj = rand_col(i, s);
        bool dup = false;
        for (int c2 = 0; c2 < nc; ++c2) dup |= (cols[c2] == rj);
        if (!dup) cols[nc++] = rj;
      }
    }
    for (int c2 = nc; c2 < 11; ++c2) cols[c2] = -1;
#pragma unroll
    for (int c2 = 0; c2 < 11; ++c2) ctab[i * 12 + c2] = cols[c2];
    ctab[i * 12 + 11] = nc;
    return;
  }
  const int idx = (bx - 8200) * 256 + t;    // 0..65535
  float s, c;
  sincosf(freqs[idx], &s, &c);
  rtab[idx] = make_float2(c, s);
}

// ---------------- GEMM common ----------------
__device__ inline void gld16(const bf16* g, bf16* l) {
  __builtin_amdgcn_global_load_lds((const __attribute__((address_space(1))) void*)g,
                                   (__attribute__((address_space(3))) void*)l, 16, 0, 0);
}

// raw barrier (no implicit vmcnt drain) + compiler memory fence
#define BAR() do { asm volatile("" ::: "memory"); __builtin_amdgcn_s_barrier(); asm volatile("" ::: "memory"); } while (0)

// ============ fused QKV GEMM, 8-phase 256x256 schedule (T3+T4+T5) ============
// Single GEMM: [4096 x 1024] x [3072 x 1024]^T (wq/wk/wv contiguous in workspace).
// 192 blocks x 512 threads (8 waves: 2M x 4N), BK=64, LDS 128 KiB (2x dbuf of
// 256x64 A + 256x64 B). Per K-tile: 4 phases, each = {stage 1 half-tile (2 gld16)
// || 4-8 ds_read_b128 -> s_barrier -> 16 MFMA under setprio -> s_barrier}.
// ONE counted vmcnt(2) per K-tile (at phase0) -- staging loads stay in flight
// across barriers (T4); never drains to 0 until the final tile.
// LDS layout identical to the verified R0 scheme: linear lane-order staging slots,
// global source pre-swizzled with kg = (s&7)^(row&7); ds_read uses the same XOR.
// Accumulation order identical to R0 -> bit-identical output.
template <int VM, bool DOSTAGE>
__device__ __forceinline__ void qkv_ktile(
    const bf16* curA, const bf16* curB, bf16* nxtA, bf16* nxtB,
    const bf16* pA, const bf16* pB, int stageK, int t8,
    int aOff, int bOff, int c0, int c1, f32x4 (&acc)[8][4]) {
  bf16x8 af[4], bv[4];

  // ---- phase 0: ks=0, m-rows 0-63 of wave tile; stage next A half0 ----
  if constexpr (DOSTAGE) {
    gld16(pA + stageK, nxtA + t8);
    gld16(pA + 65536 + stageK, nxtA + 4096 + t8);
  }
  asm volatile("s_waitcnt vmcnt(%0)" :: "n"(VM) : "memory");
  BAR();
#pragma unroll
  for (int i = 0; i < 4; ++i) af[i] = *(const bf16x8*)(curA + aOff + i * 1024 + c0);
#pragma unroll
  for (int n = 0; n < 4; ++n) bv[n] = *(const bf16x8*)(curB + bOff + n * 1024 + c0);
  __builtin_amdgcn_s_setprio(1);
#pragma unroll
  for (int i = 0; i < 4; ++i)
#pragma unroll
    for (int n = 0; n < 4; ++n)
      acc[i][n] = __builtin_amdgcn_mfma_f32_16x16x32_bf16(af[i], bv[n], acc[i][n], 0, 0, 0);
  __builtin_amdgcn_s_setprio(0);
  BAR();

  // ---- phase 1: ks=0, m-rows 64-127; stage next A half1 ----
#pragma unroll
  for (int i = 0; i < 4; ++i) af[i] = *(const bf16x8*)(curA + aOff + (4 + i) * 1024 + c0);
  if constexpr (DOSTAGE) {
    gld16(pA + 131072 + stageK, nxtA + 8192 + t8);
    gld16(pA + 196608 + stageK, nxtA + 12288 + t8);
  }
  BAR();
  __builtin_amdgcn_s_setprio(1);
#pragma unroll
  for (int i = 0; i < 4; ++i)
#pragma unroll
    for (int n = 0; n < 4; ++n)
      acc[4 + i][n] = __builtin_amdgcn_mfma_f32_16x16x32_bf16(af[i], bv[n], acc[4 + i][n], 0, 0, 0);
  __builtin_amdgcn_s_setprio(0);
  BAR();

  // ---- phase 2: ks=1, m-rows 0-63; stage next B half0 ----
#pragma unroll
  for (int i = 0; i < 4; ++i) af[i] = *(const bf16x8*)(curA + aOff + i * 1024 + c1);
#pragma unroll
  for (int n = 0; n < 4; ++n) bv[n] = *(const bf16x8*)(curB + bOff + n * 1024 + c1);
  if constexpr (DOSTAGE) {
    gld16(pB + stageK, nxtB + t8);
    gld16(pB + 65536 + stageK, nxtB + 4096 + t8);
  }
  BAR();
  __builtin_amdgcn_s_setprio(1);
#pragma unroll
  for (int i = 0; i < 4; ++i)
#pragma unroll
    for (int n = 0; n < 4; ++n)
      acc[i][n] = __builtin_amdgcn_mfma_f32_16x16x32_bf16(af[i], bv[n], acc[i][n], 0, 0, 0);
  __builtin_amdgcn_s_setprio(0);
  BAR();

  // ---- phase 3: ks=1, m-rows 64-127; stage next B half1 ----
#pragma unroll
  for (int i = 0; i < 4; ++i) af[i] = *(const bf16x8*)(curA + aOff + (4 + i) * 1024 + c1);
  if constexpr (DOSTAGE) {
    gld16(pB + 131072 + stageK, nxtB + 8192 + t8);
    gld16(pB + 196608 + stageK, nxtB + 12288 + t8);
  }
  BAR();
  __builtin_amdgcn_s_setprio(1);
#pragma unroll
  for (int i = 0; i < 4; ++i)
#pragma unroll
    for (int n = 0; n < 4; ++n)
      acc[4 + i][n] = __builtin_amdgcn_mfma_f32_16x16x32_bf16(af[i], bv[n], acc[4 + i][n], 0, 0, 0);
  __builtin_amdgcn_s_setprio(0);
  BAR();
}

__global__ __launch_bounds__(512, 2) void qkv_gemm_kernel(
    const bf16* __restrict__ xb, const bf16* __restrict__ wqkv,
    bf16* __restrict__ qb, bf16* __restrict__ kb, bf16* __restrict__ vb,
    const float2* __restrict__ rtab) {
  __shared__ __align__(16) bf16 Al[2][256 * 64];   // 2 x 32 KB
  __shared__ __align__(16) bf16 Bl[2][256 * 64];   // 2 x 32 KB

  const int t = threadIdx.x;
  const int lane = t & 63;
  const int l15 = lane & 15;
  const int kq = lane >> 4;
  const int w = t >> 6;
  const int wm = w >> 2;          // 0..1 : M half (128 rows)
  const int wn = w & 3;           // 0..3 : N quarter (64 cols)

  // XCD-aware bijective swizzle over 192 blocks (192 % 8 == 0)
  int id = blockIdx.x;
  id = (id & 7) * 24 + (id >> 3);
  const int bx = id / 12;
  const int by = id % 12;
  const int m0 = bx * 256;
  const int n0g = by * 256;       // 0..3071 across concat(wq,wk,wv)

  // staging source: slot s0 = t -> row r0 = t>>3, phys k-slot = t&7,
  // pre-swizzled logical k-chunk kg0 = (t&7)^(r0&7). Load1 (slot 512+t) is
  // row r0+64, same kg -> src offset +64*1024.
  const int r0 = t >> 3;
  const int kg0 = (t & 7) ^ (r0 & 7);
  const bf16* pA = xb + (size_t)(m0 + r0) * KD + kg0 * 8;
  const bf16* pB = wqkv + (size_t)(n0g + r0) * KD + kg0 * 8;
  const int t8 = t * 8;

  const int aOff = (wm * 128 + l15) * 64;
  const int bOff = (wn * 64 + l15) * 64;
  const int swz = l15 & 7;
  const int c0 = (kq ^ swz) * 8;          // ks=0 16B-slot (XOR-deswizzle)
  const int c1 = ((4 + kq) ^ swz) * 8;    // ks=1

  f32x4 acc[8][4] = {};

  bf16* A0 = &Al[0][0]; bf16* A1 = &Al[1][0];
  bf16* B0 = &Bl[0][0]; bf16* B1 = &Bl[1][0];

  // prologue: stage K-tile 0 into buffer 0 (8 loads in flight)
  gld16(pA, A0 + t8);
  gld16(pA + 65536, A0 + 4096 + t8);
  gld16(pA + 131072, A0 + 8192 + t8);
  gld16(pA + 196608, A0 + 12288 + t8);
  gld16(pB, B0 + t8);
  gld16(pB + 65536, B0 + 4096 + t8);
  gld16(pB + 131072, B0 + 8192 + t8);
  gld16(pB + 196608, B0 + 12288 + t8);

  for (int kt = 0; kt < 14; kt += 2) {
    qkv_ktile<2, true>(A0, B0, A1, B1, pA, pB, (kt + 1) * 64, t8, aOff, bOff, c0, c1, acc);
    qkv_ktile<2, true>(A1, B1, A0, B0, pA, pB, (kt + 2) * 64, t8, aOff, bOff, c0, c1, acc);
  }
  qkv_ktile<2, true>(A0, B0, A1, B1, pA, pB, 15 * 64, t8, aOff, bOff, c0, c1, acc);   // tile 14
  qkv_ktile<0, false>(A1, B1, A0, B0, pA, pB, 0, t8, aOff, bOff, c0, c1, acc);        // tile 15

  // ---- epilogue: RoPE (q,k) / passthrough (v), pair-store via lane shuffle ----
  // C/D layout: col = lane&15, row = (lane>>4)*4 + reg   [verified m89]
  const int j = by >> 2;                   // 0=q 1=k 2=v (256-col tile within one matrix)
  bf16* D = (j == 0) ? qb : (j == 1 ? kb : vb);
  const bool dorope = (j < 2);
  const int colb = (by & 3) * 256 + wn * 64 + l15;
  const int rowb = m0 + wm * 128 + (lane >> 4) * 4;
  const int odd = l15 & 1;
#pragma unroll
  for (int mf = 0; mf < 8; ++mf)
#pragma unroll
    for (int nf = 0; nf < 4; ++nf) {
      const int col = colb + nf * 16;
      const int jj = (col & 63) >> 1;
#pragma unroll
      for (int rr = 0; rr < 4; ++rr) {
        float val = acc[mf][nf][rr];
        float other = __shfl_xor(val, 1);    // partner column value
        if (!odd) {
          const int row = rowb + mf * 16 + rr;
          float lo, hi;
          if (dorope) {
            float2 cs = rtab[(row & (SEQ_L - 1)) * 32 + jj];
            lo = val * cs.x - other * cs.y;  // out_re
            hi = val * cs.y + other * cs.x;  // out_im
          } else { lo = val; hi = other; }
          bf16x2 p2; p2[0] = (bf16)lo; p2[1] = (bf16)hi;
          *(bf16x2*)(D + (size_t)row * ND + col) = p2;
        }
      }
    }
}

// ---- out-projection GEMM: 64x128 tile, BK=64, swizzled; grid (64,8) = 512 blocks ----
// Blocks x==0 / x==32 first materialize row-0 attention output from (pm,pz,pv).
__global__ __launch_bounds__(256, 2) void out_gemm_kernel(
    bf16* __restrict__ ab, const bf16* __restrict__ wob, float* __restrict__ out,
    const float* __restrict__ pm, const float* __restrict__ pz, const float* __restrict__ pv) {
  const int t = threadIdx.x;
  const int m0 = blockIdx.x * 64;
  const int n0 = blockIdx.y * 128;

  if (blockIdx.x == 0 || blockIdx.x == 32) {
    const int b = blockIdx.x == 0 ? 0 : 1;
#pragma unroll
    for (int e = t; e < DM; e += 256) {
      const int h = e >> 6, d = e & 63;
      const int base = b * 128 + h * 8;
      float M = -1e30f;
#pragma unroll
      for (int c = 0; c < 8; ++c) M = fmaxf(M, pm[base + c]);
      float Z = 0.f, od = 0.f;
#pragma unroll
      for (int c = 0; c < 8; ++c) {
        float sc = __expf(pm[base + c] - M);
        Z += pz[base + c] * sc;
        od += pv[(base + c) * 64 + d] * sc;
      }
      ab[(size_t)b * SEQ_L * DM + e] = (bf16)(od / Z);
    }
    __syncthreads();   // drain stores before staging reads the same row
  }

  __shared__ __align__(16) bf16 As[64 * 64];    // 8 KB
  __shared__ __align__(16) bf16 Bs[128 * 64];   // 16 KB
  const int lane = t & 63;
  const int wave = t >> 6;
  const int wm = (wave >> 1) * 32;
  const int wn = (wave & 1) * 64;
  const int l15 = lane & 15;
  const int kq = lane >> 4;

  f32x4 acc[2][4] = {};

  for (int k0 = 0; k0 < KD; k0 += 64) {
#pragma unroll
    for (int n = 0; n < 2; ++n) {
      const int s = n * 256 + t;               // 512 slots for As
      const int row = s >> 3;                  // 0..63
      const int ch = (s & 7) ^ (row & 7);
      gld16(ab + (size_t)(m0 + row) * KD + k0 + ch * 8, As + s * 8);
    }
#pragma unroll
    for (int n = 0; n < 4; ++n) {
      const int s = n * 256 + t;               // 1024 slots for Bs
      const int row = s >> 3;                  // 0..127
      const int ch = (s & 7) ^ (row & 7);
      gld16(wob + (size_t)(n0 + row) * KD + k0 + ch * 8, Bs + s * 8);
    }
    __syncthreads();
#pragma unroll
    for (int ks = 0; ks < 2; ++ks) {
      const int cb = ks * 4 + kq;
      bf16x8 af[2], bfr[4];
#pragma unroll
      for (int mt = 0; mt < 2; ++mt) {
        const int row = wm + mt * 16 + l15;
        af[mt] = *(const bf16x8*)(As + row * 64 + ((cb ^ (row & 7)) * 8));
      }
#pragma unroll
      for (int nt = 0; nt < 4; ++nt) {
        const int row = wn + nt * 16 + l15;
        bfr[nt] = *(const bf16x8*)(Bs + row * 64 + ((cb ^ (row & 7)) * 8));
      }
#pragma unroll
      for (int mt = 0; mt < 2; ++mt)
#pragma unroll
        for (int nt = 0; nt < 4; ++nt)
          acc[mt][nt] = __builtin_amdgcn_mfma_f32_16x16x32_bf16(af[mt], bfr[nt], acc[mt][nt], 0, 0, 0);
    }
    __syncthreads();
  }
  const int colb = n0 + wn + l15;
  const int rowb = m0 + wm + (lane >> 4) * 4;
#pragma unroll
  for (int mt = 0; mt < 2; ++mt)
#pragma unroll
    for (int nt = 0; nt < 4; ++nt)
#pragma unroll
      for (int rr = 0; rr < 4; ++rr)
        out[(size_t)(rowb + mt * 16 + rr) * ND + colb + nt * 16] = acc[mt][nt][rr];
}

// ---------------- attention ----------------
// grid (1280, 1), 256 threads.
//  bx < 256  : row-0 partials per (b, h, 256-col chunk) -> pm/pz/pv (dispatched FIRST: no tail).
//  bx >= 256 : sparse rows; wave handles one row i for ALL 16 heads (2KB wave-loads);
//              ALL 44 k+v load-quads prefetched into registers before any use (ILP).
__global__ __launch_bounds__(256, 2) void attn_kernel(const bf16* __restrict__ q, const bf16* __restrict__ k,
                                                      const bf16* __restrict__ v, bf16* __restrict__ o,
                                                      const int* __restrict__ ctab,
                                                      float* __restrict__ pm, float* __restrict__ pz,
                                                      float* __restrict__ pv) {
  const int t = threadIdx.x;
  const int lane = t & 63;
  const int w = t >> 6;

  __shared__ float sbuf[256];
  __shared__ float redm[4], redz[4];
  __shared__ float part[4][64];

  if (blockIdx.x >= 256) {
    const int sbx = blockIdx.x - 256;               // 0..1023
    const int b = sbx >> 9;
    const int tt = sbx & 511;
    const int tile = ((tt & 7) << 6) + (tt >> 3);   // XCD swizzle
    const int i = tile * 4 + 1 + w;
    if (i >= SEQ_L) return;   // wave-uniform
    const size_t bb = (size_t)b * SEQ_L * DM;
    const int eo = lane * 16;

    const bf16* qrow = q + bb + (size_t)i * DM + eo;
    bf16x8 qv0 = *(const bf16x8*)(qrow);
    bf16x8 qv1 = *(const bf16x8*)(qrow + 8);

    const int4* cp = (const int4*)(ctab + i * 12);
    int4 ca = cp[0], cb = cp[1], cc = cp[2];
    int cols[11] = {ca.x, ca.y, ca.z, ca.w, cb.x, cb.y, cb.z, cb.w, cc.x, cc.y, cc.z};

    // prefetch ALL k and v rows into registers (44 independent 16B loads in flight)
    bf16x8 kv[11][2], vv[11][2];
#pragma unroll
    for (int c = 0; c < 11; ++c) {
      int cj = cols[c] < 0 ? 0 : cols[c];
      const bf16* krow = k + bb + (size_t)cj * DM + eo;
      kv[c][0] = *(const bf16x8*)(krow);
      kv[c][1] = *(const bf16x8*)(krow + 8);
    }
#pragma unroll
    for (int c = 0; c < 11; ++c) {
      int cj = cols[c] < 0 ? 0 : cols[c];
      const bf16* vrow = v + bb + (size_t)cj * DM + eo;
      vv[c][0] = *(const bf16x8*)(vrow);
      vv[c][1] = *(const bf16x8*)(vrow + 8);
    }

    float sv[11];
#pragma unroll
    for (int c = 0; c < 11; ++c) {
      float acc = 0.f;
#pragma unroll
      for (int e = 0; e < 8; ++e)
        acc += (float)qv0[e] * (float)kv[c][0][e] + (float)qv1[e] * (float)kv[c][1][e];
      sv[c] = acc;
    }
#pragma unroll
    for (int c = 0; c < 11; ++c) {
      sv[c] += __shfl_xor(sv[c], 1);
      sv[c] += __shfl_xor(sv[c], 2);
      sv[c] = cols[c] < 0 ? -1e30f : sv[c] * 0.125f;
    }
    float m = -1e30f;
#pragma unroll
    for (int c = 0; c < 11; ++c) m = fmaxf(m, sv[c]);
    float z = 0.f;
#pragma unroll
    for (int c = 0; c < 11; ++c) { sv[c] = __expf(sv[c] - m); z += sv[c]; }
    const float inv = 1.f / z;

    float oa[16] = {};
#pragma unroll
    for (int c = 0; c < 11; ++c) {
#pragma unroll
      for (int e = 0; e < 8; ++e) {
        oa[e]     += sv[c] * (float)vv[c][0][e];
        oa[8 + e] += sv[c] * (float)vv[c][1][e];
      }
    }
    bf16x8 ov0, ov1;
#pragma unroll
    for (int e = 0; e < 8; ++e) {
      ov0[e] = (bf16)(oa[e] * inv);
      ov1[e] = (bf16)(oa[8 + e] * inv);
    }
    bf16* orow = o + bb + (size_t)i * DM + eo;
    *(bf16x8*)(orow) = ov0;
    *(bf16x8*)(orow + 8) = ov1;
    return;
  }

  // ---- row-0 partial: (b, h, chunk of 256 cols) ----
  const int idx = blockIdx.x;           // 0..255
  const int b = idx >> 7;
  const int rem = idx & 127;
  const int h = rem >> 3;
  const int c = rem & 7;
  const size_t hb = (size_t)b * SEQ_L * DM + (size_t)h * HD;
  const int j = c * 256 + t;

  bf16x8 qv8[8];
#pragma unroll
  for (int cc = 0; cc < 8; ++cc) qv8[cc] = *(const bf16x8*)(q + hb + cc * 8);

  float acc = 0.f;
#pragma unroll
  for (int cc = 0; cc < 8; ++cc) {
    bf16x8 kv = *(const bf16x8*)(k + hb + (size_t)j * DM + cc * 8);
#pragma unroll
    for (int e = 0; e < 8; ++e) acc += (float)qv8[cc][e] * (float)kv[e];
  }
  float s = acc * 0.125f;
  float mloc = s;
#pragma unroll
  for (int off = 32; off > 0; off >>= 1) mloc = fmaxf(mloc, __shfl_xor(mloc, off));
  if (lane == 0) redm[w] = mloc;
  __syncthreads();
  const float m = fmaxf(fmaxf(redm[0], redm[1]), fmaxf(redm[2], redm[3]));

  float e = __expf(s - m);
  sbuf[t] = e;
  float zloc = e;
#pragma unroll
  for (int off = 32; off > 0; off >>= 1) zloc += __shfl_xor(zloc, off);
  if (lane == 0) redz[w] = zloc;
  __syncthreads();
  const float zc = redz[0] + redz[1] + redz[2] + redz[3];

  float oa = 0.f;
  for (int jj = w; jj < 256; jj += 4)
    oa += sbuf[jj] * (float)v[hb + (size_t)(c * 256 + jj) * DM + lane];
  part[w][lane] = oa;
  __syncthreads();
  if (t < 64) pv[idx * 64 + t] = part[0][t] + part[1][t] + part[2][t] + part[3][t];
  if (t == 0) { pm[idx] = m; pz[idx] = zc; }
}

// ---------------- launch ----------------
extern "C" void kernel_launch(void* const* d_in, const int* in_sizes, int n_in,
                              void* d_out, int out_size, void* d_ws, size_t ws_size,
                              hipStream_t stream) {
  const float* x     = (const float*)d_in[0];
  const float* freqs = (const float*)d_in[1];
  const float* wq    = (const float*)d_in[2];
  const float* wk    = (const float*)d_in[3];
  const float* wv    = (const float*)d_in[4];
  const float* wo    = (const float*)d_in[5];
  float* out = (float*)d_out;

  char* ws = (char*)d_ws;
  bf16* xb  = (bf16*)(ws + 0);          // 8 MiB
  bf16* wqb = (bf16*)(ws + 8388608);    // 2 MiB each; wq/wk/wv contiguous = wqkv [3072][1024]
  bf16* wkb = (bf16*)(ws + 10485760);
  bf16* wvb = (bf16*)(ws + 12582912);
  bf16* wob = (bf16*)(ws + 14680064);
  bf16* qb  = (bf16*)(ws + 16777216);   // 8 MiB [B,L,H,HD]
  bf16* kb  = (bf16*)(ws + 25165824);
  bf16* vb  = (bf16*)(ws + 33554432);
  bf16* ab  = (bf16*)(ws + 41943040);   // 8 MiB; end 48 MiB
  int*    ctab = (int*)(ws + 50331648); // 96 KB
  float*  pm   = (float*)(ws + 50462720);
  float*  pz   = (float*)(ws + 50463744);
  float*  pv   = (float*)(ws + 50464768);   // 64 KB
  float2* rtab = (float2*)(ws + 50593792);  // 512 KB rope cos/sin table
  (void)ws_size;

  prep_kernel<<<8456, 256, 0, stream>>>(x, wq, wk, wv, wo, freqs, xb, wqb, wkb, wvb, wob, ctab, rtab);
  qkv_gemm_kernel<<<dim3(192), 512, 0, stream>>>(xb, wqb, qb, kb, vb, rtab);
  attn_kernel<<<dim3(1280, 1), 256, 0, stream>>>(qb, kb, vb, ab, ctab, pm, pz, pv);
  out_gemm_kernel<<<dim3(64, 8), 256, 0, stream>>>(ab, wob, out, pm, pz, pv);
}

// Round 3
// 165.056 us; speedup vs baseline: 1.1351x; 1.1351x over previous
//
#include <hip/hip_runtime.h>
#include <math.h>

#define SEQ_L 2048
#define DM 1024
#define NH 16
#define HD 64
#define NB 2
#define KD 1024   // GEMM K
#define ND 1024   // GEMM N

typedef __bf16 bf16;
typedef __bf16 bf16x8 __attribute__((ext_vector_type(8)));
typedef __bf16 bf16x4 __attribute__((ext_vector_type(4)));
typedef __bf16 bf16x2 __attribute__((ext_vector_type(2)));
typedef float f32x4 __attribute__((ext_vector_type(4)));

// ---------------- jax threefry2x32, key = (0, 42); partitionable random_bits ----------------
__device__ inline uint32_t rotl32(uint32_t v, int n) { return (v << n) | (v >> (32 - n)); }

__device__ inline void threefry(uint32_t x0, uint32_t x1, uint32_t* o0, uint32_t* o1) {
  const uint32_t ks0 = 0u, ks1 = 42u, ks2 = 0u ^ 42u ^ 0x1BD11BDAu;
  x0 += ks0; x1 += ks1;
#define TF_R(rr) { x0 += x1; x1 = rotl32(x1, rr); x1 ^= x0; }
  TF_R(13) TF_R(15) TF_R(26) TF_R(6)
  x0 += ks1; x1 += ks2 + 1u;
  TF_R(17) TF_R(29) TF_R(16) TF_R(24)
  x0 += ks2; x1 += ks0 + 2u;
  TF_R(13) TF_R(15) TF_R(26) TF_R(6)
  x0 += ks0; x1 += ks1 + 3u;
  TF_R(17) TF_R(29) TF_R(16) TF_R(24)
  x0 += ks1; x1 += ks2 + 4u;
  TF_R(13) TF_R(15) TF_R(26) TF_R(6)
  x0 += ks2; x1 += ks0 + 5u;
#undef TF_R
  *o0 = x0; *o1 = x1;
}

// jax_threefry_partitionable=True: counter (hi=0, lo=flat_idx), bits = o0 ^ o1.
__device__ inline int rand_col(int i, int s) {
  uint32_t o0, o1;
  threefry(0u, (uint32_t)(2 * i + s), &o0, &o1);
  uint32_t bits = o0 ^ o1;
  float u = __uint_as_float((bits >> 9) | 0x3f800000u) - 1.0f;
  return (int)floorf(u * (float)(i + 1));
}

// ---------------- prep: conversions + ctab + rope cos/sin table ----------------
__global__ void prep_kernel(const float* __restrict__ x,
                            const float* __restrict__ w0, const float* __restrict__ w1,
                            const float* __restrict__ w2, const float* __restrict__ w3,
                            const float* __restrict__ freqs,
                            bf16* __restrict__ xb,
                            bf16* __restrict__ o0, bf16* __restrict__ o1,
                            bf16* __restrict__ o2, bf16* __restrict__ o3,
                            int* __restrict__ ctab, float2* __restrict__ rtab) {
  const int bx = blockIdx.x;
  const int t = threadIdx.x;
  if (bx < 8192) {
    const float* src;
    bf16* dst;
    int idx;
    if (bx < 4096) { src = x; dst = xb; idx = bx * 256 + t; }
    else {
      int widx = bx - 4096;
      int wsel = widx >> 10;
      switch (wsel) {
        case 0: src = w0; dst = o0; break;
        case 1: src = w1; dst = o1; break;
        case 2: src = w2; dst = o2; break;
        default: src = w3; dst = o3; break;
      }
      idx = (widx & 1023) * 256 + t;
    }
    float4 vv = ((const float4*)src)[idx];
    bf16x4 ov;
    ov[0] = (bf16)vv.x; ov[1] = (bf16)vv.y; ov[2] = (bf16)vv.z; ov[3] = (bf16)vv.w;
    *(bf16x4*)(dst + (size_t)idx * 4) = ov;
    return;
  }
  if (bx < 8200) {
    const int i = (bx - 8192) * 256 + t;    // 0..2047
    int cols[11]; int nc = 0;
    if (i >= 1) {
      int lo = i - 7; if (lo < 0) lo = 0;
      for (int j = lo; j <= i; ++j) cols[nc++] = j;
      if (lo > 0) cols[nc++] = 0;
#pragma unroll
      for (int s = 0; s < 2; ++s) {
        int rj = rand_col(i, s);
        bool dup = false;
        for (int c2 = 0; c2 < nc; ++c2) dup |= (cols[c2] == rj);
        if (!dup) cols[nc++] = rj;
      }
    }
    for (int c2 = nc; c2 < 11; ++c2) cols[c2] = -1;
#pragma unroll
    for (int c2 = 0; c2 < 11; ++c2) ctab[i * 12 + c2] = cols[c2];
    ctab[i * 12 + 11] = nc;
    return;
  }
  const int idx = (bx - 8200) * 256 + t;    // 0..65535
  float s, c;
  sincosf(freqs[idx], &s, &c);
  rtab[idx] = make_float2(c, s);
}

// ---------------- GEMM common ----------------
__device__ inline void gld16(const bf16* g, bf16* l) {
  __builtin_amdgcn_global_load_lds((const __attribute__((address_space(1))) void*)g,
                                   (__attribute__((address_space(3))) void*)l, 16, 0, 0);
}

// ============ QKV GEMM: m97-verified structure (874-912 TF ladder step 3) ============
// Single un-fused GEMM [4096 x 1024] x [3072 x 1024]^T over contiguous wq/wk/wv.
// 128x128 tile, BK=64, 4 waves x (64x64 wave tile, acc[4][4]), 32 KB single-buffered
// LDS, global_load_lds width=16, XOR-swizzled (same verified scheme as before).
// Grid 32x24 = 768 blocks = exactly 3 blocks/CU (12 waves/CU), 768%8==0 for XCD swizzle.
// Per-output-element K-accumulation order identical to the fused 64x64 version ->
// bit-identical q/k/v.
__global__ __launch_bounds__(256, 3) void qkv_gemm_kernel(
    const bf16* __restrict__ xb, const bf16* __restrict__ wqkv,
    bf16* __restrict__ qb, bf16* __restrict__ kb, bf16* __restrict__ vb,
    const float2* __restrict__ rtab) {
  __shared__ __align__(16) bf16 As[128 * 64];   // 16 KB
  __shared__ __align__(16) bf16 Bs[128 * 64];   // 16 KB

  const int t = threadIdx.x;
  const int lane = t & 63;
  const int w = t >> 6;            // 4 waves
  const int wm = (w >> 1) * 64;    // wave tile: 64(m) x 64(n)
  const int wn = (w & 1) * 64;
  const int l15 = lane & 15;
  const int kq = lane >> 4;        // 0..3

  // XCD-aware bijective swizzle over 768 blocks (768 % 8 == 0)
  int id = blockIdx.x;
  id = (id & 7) * 96 + (id >> 3);
  const int bx = id / 24;          // 0..31 (m tiles)
  const int by = id % 24;          // 0..23 (n tiles over concat q,k,v)
  const int m0 = bx * 128;
  const int n0g = by * 128;

  f32x4 acc[4][4] = {};

  for (int k0 = 0; k0 < KD; k0 += 64) {
    // A: 128x64 = 1024 slots of 16B, 4/thread
#pragma unroll
    for (int n = 0; n < 4; ++n) {
      const int s = n * 256 + t;
      const int row = s >> 3;                  // 0..127
      const int ch = (s & 7) ^ (row & 7);      // XOR bank swizzle
      gld16(xb + (size_t)(m0 + row) * KD + k0 + ch * 8, As + s * 8);
    }
    // B: 128x64 = 1024 slots, 4/thread
#pragma unroll
    for (int n = 0; n < 4; ++n) {
      const int s = n * 256 + t;
      const int row = s >> 3;                  // 0..127
      const int ch = (s & 7) ^ (row & 7);
      gld16(wqkv + (size_t)(n0g + row) * KD + k0 + ch * 8, Bs + s * 8);
    }
    __syncthreads();
#pragma unroll
    for (int ks = 0; ks < 2; ++ks) {
      const int cb = ks * 4 + kq;              // k-chunk 0..7
      bf16x8 af[4], bv[4];
#pragma unroll
      for (int mt = 0; mt < 4; ++mt) {
        const int row = wm + mt * 16 + l15;
        af[mt] = *(const bf16x8*)(As + row * 64 + ((cb ^ (row & 7)) * 8));
      }
#pragma unroll
      for (int nt = 0; nt < 4; ++nt) {
        const int row = wn + nt * 16 + l15;
        bv[nt] = *(const bf16x8*)(Bs + row * 64 + ((cb ^ (row & 7)) * 8));
      }
#pragma unroll
      for (int mt = 0; mt < 4; ++mt)
#pragma unroll
        for (int nt = 0; nt < 4; ++nt)
          acc[mt][nt] = __builtin_amdgcn_mfma_f32_16x16x32_bf16(af[mt], bv[nt], acc[mt][nt], 0, 0, 0);
    }
    __syncthreads();
  }

  // ---- epilogue: RoPE (q,k) / passthrough (v), pair-store via lane shuffle ----
  // C/D layout: col = lane&15, row = (lane>>4)*4 + reg   [verified m89]
  const int j = by >> 3;                   // 0=q 1=k 2=v (8 n-tiles per matrix)
  bf16* D = (j == 0) ? qb : (j == 1 ? kb : vb);
  const bool dorope = (j < 2);
  const int colb = (by & 7) * 128 + wn + l15;   // column within the matrix (0..1023)
  const int rowb = m0 + wm + (lane >> 4) * 4;
  const int odd = l15 & 1;
#pragma unroll
  for (int mf = 0; mf < 4; ++mf)
#pragma unroll
    for (int nf = 0; nf < 4; ++nf) {
      const int col = colb + nf * 16;
      const int jj = (col & 63) >> 1;
#pragma unroll
      for (int rr = 0; rr < 4; ++rr) {
        float val = acc[mf][nf][rr];
        float other = __shfl_xor(val, 1);    // partner column value
        if (!odd) {
          const int row = rowb + mf * 16 + rr;
          float lo, hi;
          if (dorope) {
            float2 cs = rtab[(row & (SEQ_L - 1)) * 32 + jj];
            lo = val * cs.x - other * cs.y;  // out_re
            hi = val * cs.y + other * cs.x;  // out_im
          } else { lo = val; hi = other; }
          bf16x2 p2; p2[0] = (bf16)lo; p2[1] = (bf16)hi;
          *(bf16x2*)(D + (size_t)row * ND + col) = p2;
        }
      }
    }
}

// ---- out-projection GEMM: 64x128 tile, BK=64, swizzled; grid (64,8) = 512 blocks ----
// Blocks x==0 / x==32 first materialize row-0 attention output from (pm,pz,pv).
__global__ __launch_bounds__(256, 2) void out_gemm_kernel(
    bf16* __restrict__ ab, const bf16* __restrict__ wob, float* __restrict__ out,
    const float* __restrict__ pm, const float* __restrict__ pz, const float* __restrict__ pv) {
  const int t = threadIdx.x;
  const int m0 = blockIdx.x * 64;
  const int n0 = blockIdx.y * 128;

  if (blockIdx.x == 0 || blockIdx.x == 32) {
    const int b = blockIdx.x == 0 ? 0 : 1;
#pragma unroll
    for (int e = t; e < DM; e += 256) {
      const int h = e >> 6, d = e & 63;
      const int base = b * 128 + h * 8;
      float M = -1e30f;
#pragma unroll
      for (int c = 0; c < 8; ++c) M = fmaxf(M, pm[base + c]);
      float Z = 0.f, od = 0.f;
#pragma unroll
      for (int c = 0; c < 8; ++c) {
        float sc = __expf(pm[base + c] - M);
        Z += pz[base + c] * sc;
        od += pv[(base + c) * 64 + d] * sc;
      }
      ab[(size_t)b * SEQ_L * DM + e] = (bf16)(od / Z);
    }
    __syncthreads();   // drain stores before staging reads the same row
  }

  __shared__ __align__(16) bf16 As[64 * 64];    // 8 KB
  __shared__ __align__(16) bf16 Bs[128 * 64];   // 16 KB
  const int lane = t & 63;
  const int wave = t >> 6;
  const int wm = (wave >> 1) * 32;
  const int wn = (wave & 1) * 64;
  const int l15 = lane & 15;
  const int kq = lane >> 4;

  f32x4 acc[2][4] = {};

  for (int k0 = 0; k0 < KD; k0 += 64) {
#pragma unroll
    for (int n = 0; n < 2; ++n) {
      const int s = n * 256 + t;               // 512 slots for As
      const int row = s >> 3;                  // 0..63
      const int ch = (s & 7) ^ (row & 7);
      gld16(ab + (size_t)(m0 + row) * KD + k0 + ch * 8, As + s * 8);
    }
#pragma unroll
    for (int n = 0; n < 4; ++n) {
      const int s = n * 256 + t;               // 1024 slots for Bs
      const int row = s >> 3;                  // 0..127
      const int ch = (s & 7) ^ (row & 7);
      gld16(wob + (size_t)(n0 + row) * KD + k0 + ch * 8, Bs + s * 8);
    }
    __syncthreads();
#pragma unroll
    for (int ks = 0; ks < 2; ++ks) {
      const int cb = ks * 4 + kq;
      bf16x8 af[2], bfr[4];
#pragma unroll
      for (int mt = 0; mt < 2; ++mt) {
        const int row = wm + mt * 16 + l15;
        af[mt] = *(const bf16x8*)(As + row * 64 + ((cb ^ (row & 7)) * 8));
      }
#pragma unroll
      for (int nt = 0; nt < 4; ++nt) {
        const int row = wn + nt * 16 + l15;
        bfr[nt] = *(const bf16x8*)(Bs + row * 64 + ((cb ^ (row & 7)) * 8));
      }
#pragma unroll
      for (int mt = 0; mt < 2; ++mt)
#pragma unroll
        for (int nt = 0; nt < 4; ++nt)
          acc[mt][nt] = __builtin_amdgcn_mfma_f32_16x16x32_bf16(af[mt], bfr[nt], acc[mt][nt], 0, 0, 0);
    }
    __syncthreads();
  }
  const int colb = n0 + wn + l15;
  const int rowb = m0 + wm + (lane >> 4) * 4;
#pragma unroll
  for (int mt = 0; mt < 2; ++mt)
#pragma unroll
    for (int nt = 0; nt < 4; ++nt)
#pragma unroll
      for (int rr = 0; rr < 4; ++rr)
        out[(size_t)(rowb + mt * 16 + rr) * ND + colb + nt * 16] = acc[mt][nt][rr];
}

// ---------------- attention ----------------
// grid (1280, 1), 256 threads.
//  bx < 256  : row-0 partials per (b, h, 256-col chunk) -> pm/pz/pv (dispatched FIRST: no tail).
//  bx >= 256 : sparse rows; wave handles one row i for ALL 16 heads (2KB wave-loads);
//              ALL 44 k+v load-quads prefetched into registers before any use (ILP).
__global__ __launch_bounds__(256, 2) void attn_kernel(const bf16* __restrict__ q, const bf16* __restrict__ k,
                                                      const bf16* __restrict__ v, bf16* __restrict__ o,
                                                      const int* __restrict__ ctab,
                                                      float* __restrict__ pm, float* __restrict__ pz,
                                                      float* __restrict__ pv) {
  const int t = threadIdx.x;
  const int lane = t & 63;
  const int w = t >> 6;

  __shared__ float sbuf[256];
  __shared__ float redm[4], redz[4];
  __shared__ float part[4][64];

  if (blockIdx.x >= 256) {
    const int sbx = blockIdx.x - 256;               // 0..1023
    const int b = sbx >> 9;
    const int tt = sbx & 511;
    const int tile = ((tt & 7) << 6) + (tt >> 3);   // XCD swizzle
    const int i = tile * 4 + 1 + w;
    if (i >= SEQ_L) return;   // wave-uniform
    const size_t bb = (size_t)b * SEQ_L * DM;
    const int eo = lane * 16;

    const bf16* qrow = q + bb + (size_t)i * DM + eo;
    bf16x8 qv0 = *(const bf16x8*)(qrow);
    bf16x8 qv1 = *(const bf16x8*)(qrow + 8);

    const int4* cp = (const int4*)(ctab + i * 12);
    int4 ca = cp[0], cb = cp[1], cc = cp[2];
    int cols[11] = {ca.x, ca.y, ca.z, ca.w, cb.x, cb.y, cb.z, cb.w, cc.x, cc.y, cc.z};

    // prefetch ALL k and v rows into registers (44 independent 16B loads in flight)
    bf16x8 kv[11][2], vv[11][2];
#pragma unroll
    for (int c = 0; c < 11; ++c) {
      int cj = cols[c] < 0 ? 0 : cols[c];
      const bf16* krow = k + bb + (size_t)cj * DM + eo;
      kv[c][0] = *(const bf16x8*)(krow);
      kv[c][1] = *(const bf16x8*)(krow + 8);
    }
#pragma unroll
    for (int c = 0; c < 11; ++c) {
      int cj = cols[c] < 0 ? 0 : cols[c];
      const bf16* vrow = v + bb + (size_t)cj * DM + eo;
      vv[c][0] = *(const bf16x8*)(vrow);
      vv[c][1] = *(const bf16x8*)(vrow + 8);
    }

    float sv[11];
#pragma unroll
    for (int c = 0; c < 11; ++c) {
      float acc = 0.f;
#pragma unroll
      for (int e = 0; e < 8; ++e)
        acc += (float)qv0[e] * (float)kv[c][0][e] + (float)qv1[e] * (float)kv[c][1][e];
      sv[c] = acc;
    }
#pragma unroll
    for (int c = 0; c < 11; ++c) {
      sv[c] += __shfl_xor(sv[c], 1);
      sv[c] += __shfl_xor(sv[c], 2);
      sv[c] = cols[c] < 0 ? -1e30f : sv[c] * 0.125f;
    }
    float m = -1e30f;
#pragma unroll
    for (int c = 0; c < 11; ++c) m = fmaxf(m, sv[c]);
    float z = 0.f;
#pragma unroll
    for (int c = 0; c < 11; ++c) { sv[c] = __expf(sv[c] - m); z += sv[c]; }
    const float inv = 1.f / z;

    float oa[16] = {};
#pragma unroll
    for (int c = 0; c < 11; ++c) {
#pragma unroll
      for (int e = 0; e < 8; ++e) {
        oa[e]     += sv[c] * (float)vv[c][0][e];
        oa[8 + e] += sv[c] * (float)vv[c][1][e];
      }
    }
    bf16x8 ov0, ov1;
#pragma unroll
    for (int e = 0; e < 8; ++e) {
      ov0[e] = (bf16)(oa[e] * inv);
      ov1[e] = (bf16)(oa[8 + e] * inv);
    }
    bf16* orow = o + bb + (size_t)i * DM + eo;
    *(bf16x8*)(orow) = ov0;
    *(bf16x8*)(orow + 8) = ov1;
    return;
  }

  // ---- row-0 partial: (b, h, chunk of 256 cols) ----
  const int idx = blockIdx.x;           // 0..255
  const int b = idx >> 7;
  const int rem = idx & 127;
  const int h = rem >> 3;
  const int c = rem & 7;
  const size_t hb = (size_t)b * SEQ_L * DM + (size_t)h * HD;
  const int j = c * 256 + t;

  bf16x8 qv8[8];
#pragma unroll
  for (int cc = 0; cc < 8; ++cc) qv8[cc] = *(const bf16x8*)(q + hb + cc * 8);

  float acc = 0.f;
#pragma unroll
  for (int cc = 0; cc < 8; ++cc) {
    bf16x8 kv = *(const bf16x8*)(k + hb + (size_t)j * DM + cc * 8);
#pragma unroll
    for (int e = 0; e < 8; ++e) acc += (float)qv8[cc][e] * (float)kv[e];
  }
  float s = acc * 0.125f;
  float mloc = s;
#pragma unroll
  for (int off = 32; off > 0; off >>= 1) mloc = fmaxf(mloc, __shfl_xor(mloc, off));
  if (lane == 0) redm[w] = mloc;
  __syncthreads();
  const float m = fmaxf(fmaxf(redm[0], redm[1]), fmaxf(redm[2], redm[3]));

  float e = __expf(s - m);
  sbuf[t] = e;
  float zloc = e;
#pragma unroll
  for (int off = 32; off > 0; off >>= 1) zloc += __shfl_xor(zloc, off);
  if (lane == 0) redz[w] = zloc;
  __syncthreads();
  const float zc = redz[0] + redz[1] + redz[2] + redz[3];

  float oa = 0.f;
  for (int jj = w; jj < 256; jj += 4)
    oa += sbuf[jj] * (float)v[hb + (size_t)(c * 256 + jj) * DM + lane];
  part[w][lane] = oa;
  __syncthreads();
  if (t < 64) pv[idx * 64 + t] = part[0][t] + part[1][t] + part[2][t] + part[3][t];
  if (t == 0) { pm[idx] = m; pz[idx] = zc; }
}

// ---------------- launch ----------------
extern "C" void kernel_launch(void* const* d_in, const int* in_sizes, int n_in,
                              void* d_out, int out_size, void* d_ws, size_t ws_size,
                              hipStream_t stream) {
  const float* x     = (const float*)d_in[0];
  const float* freqs = (const float*)d_in[1];
  const float* wq    = (const float*)d_in[2];
  const float* wk    = (const float*)d_in[3];
  const float* wv    = (const float*)d_in[4];
  const float* wo    = (const float*)d_in[5];
  float* out = (float*)d_out;

  char* ws = (char*)d_ws;
  bf16* xb  = (bf16*)(ws + 0);          // 8 MiB
  bf16* wqb = (bf16*)(ws + 8388608);    // 2 MiB each; wq/wk/wv contiguous = wqkv [3072][1024]
  bf16* wkb = (bf16*)(ws + 10485760);
  bf16* wvb = (bf16*)(ws + 12582912);
  bf16* wob = (bf16*)(ws + 14680064);
  bf16* qb  = (bf16*)(ws + 16777216);   // 8 MiB [B,L,H,HD]
  bf16* kb  = (bf16*)(ws + 25165824);
  bf16* vb  = (bf16*)(ws + 33554432);
  bf16* ab  = (bf16*)(ws + 41943040);   // 8 MiB; end 48 MiB
  int*    ctab = (int*)(ws + 50331648); // 96 KB
  float*  pm   = (float*)(ws + 50462720);
  float*  pz   = (float*)(ws + 50463744);
  float*  pv   = (float*)(ws + 50464768);   // 64 KB
  float2* rtab = (float2*)(ws + 50593792);  // 512 KB rope cos/sin table
  (void)ws_size;

  prep_kernel<<<8456, 256, 0, stream>>>(x, wq, wk, wv, wo, freqs, xb, wqb, wkb, wvb, wob, ctab, rtab);
  qkv_gemm_kernel<<<dim3(768), 256, 0, stream>>>(xb, wqb, qb, kb, vb, rtab);
  attn_kernel<<<dim3(1280, 1), 256, 0, stream>>>(qb, kb, vb, ab, ctab, pm, pz, pv);
  out_gemm_kernel<<<dim3(64, 8), 256, 0, stream>>>(ab, wob, out, pm, pz, pv);
}

// Round 5
// 160.781 us; speedup vs baseline: 1.1652x; 1.0266x over previous
//
#include <hip/hip_runtime.h>
#include <math.h>

#define SEQ_L 2048
#define DM 1024
#define NH 16
#define HD 64
#define NB 2
#define KD 1024   // GEMM K
#define ND 1024   // GEMM N

typedef __bf16 bf16;
typedef __bf16 bf16x8 __attribute__((ext_vector_type(8)));
typedef __bf16 bf16x4 __attribute__((ext_vector_type(4)));
typedef __bf16 bf16x2 __attribute__((ext_vector_type(2)));
typedef float f32x4 __attribute__((ext_vector_type(4)));

// ---------------- jax threefry2x32, key = (0, 42); partitionable random_bits ----------------
__device__ inline uint32_t rotl32(uint32_t v, int n) { return (v << n) | (v >> (32 - n)); }

__device__ inline void threefry(uint32_t x0, uint32_t x1, uint32_t* o0, uint32_t* o1) {
  const uint32_t ks0 = 0u, ks1 = 42u, ks2 = 0u ^ 42u ^ 0x1BD11BDAu;
  x0 += ks0; x1 += ks1;
#define TF_R(rr) { x0 += x1; x1 = rotl32(x1, rr); x1 ^= x0; }
  TF_R(13) TF_R(15) TF_R(26) TF_R(6)
  x0 += ks1; x1 += ks2 + 1u;
  TF_R(17) TF_R(29) TF_R(16) TF_R(24)
  x0 += ks2; x1 += ks0 + 2u;
  TF_R(13) TF_R(15) TF_R(26) TF_R(6)
  x0 += ks0; x1 += ks1 + 3u;
  TF_R(17) TF_R(29) TF_R(16) TF_R(24)
  x0 += ks1; x1 += ks2 + 4u;
  TF_R(13) TF_R(15) TF_R(26) TF_R(6)
  x0 += ks2; x1 += ks0 + 5u;
#undef TF_R
  *o0 = x0; *o1 = x1;
}

// jax_threefry_partitionable=True: counter (hi=0, lo=flat_idx), bits = o0 ^ o1.
__device__ inline int rand_col(int i, int s) {
  uint32_t o0, o1;
  threefry(0u, (uint32_t)(2 * i + s), &o0, &o1);
  uint32_t bits = o0 ^ o1;
  float u = __uint_as_float((bits >> 9) | 0x3f800000u) - 1.0f;
  return (int)floorf(u * (float)(i + 1));
}

// ---------------- prep: conversions + ctab + rope cos/sin table ----------------
__global__ void prep_kernel(const float* __restrict__ x,
                            const float* __restrict__ w0, const float* __restrict__ w1,
                            const float* __restrict__ w2, const float* __restrict__ w3,
                            const float* __restrict__ freqs,
                            bf16* __restrict__ xb,
                            bf16* __restrict__ o0, bf16* __restrict__ o1,
                            bf16* __restrict__ o2, bf16* __restrict__ o3,
                            int* __restrict__ ctab, float2* __restrict__ rtab) {
  const int bx = blockIdx.x;
  const int t = threadIdx.x;
  if (bx < 8192) {
    const float* src;
    bf16* dst;
    int idx;
    if (bx < 4096) { src = x; dst = xb; idx = bx * 256 + t; }
    else {
      int widx = bx - 4096;
      int wsel = widx >> 10;
      switch (wsel) {
        case 0: src = w0; dst = o0; break;
        case 1: src = w1; dst = o1; break;
        case 2: src = w2; dst = o2; break;
        default: src = w3; dst = o3; break;
      }
      idx = (widx & 1023) * 256 + t;
    }
    float4 vv = ((const float4*)src)[idx];
    bf16x4 ov;
    ov[0] = (bf16)vv.x; ov[1] = (bf16)vv.y; ov[2] = (bf16)vv.z; ov[3] = (bf16)vv.w;
    *(bf16x4*)(dst + (size_t)idx * 4) = ov;
    return;
  }
  if (bx < 8200) {
    const int i = (bx - 8192) * 256 + t;    // 0..2047
    int cols[11]; int nc = 0;
    if (i >= 1) {
      int lo = i - 7; if (lo < 0) lo = 0;
      for (int j = lo; j <= i; ++j) cols[nc++] = j;
      if (lo > 0) cols[nc++] = 0;
#pragma unroll
      for (int s = 0; s < 2; ++s) {
        int rj = rand_col(i, s);
        bool dup = false;
        for (int c2 = 0; c2 < nc; ++c2) dup |= (cols[c2] == rj);
        if (!dup) cols[nc++] = rj;
      }
    }
    for (int c2 = nc; c2 < 11; ++c2) cols[c2] = -1;
#pragma unroll
    for (int c2 = 0; c2 < 11; ++c2) ctab[i * 12 + c2] = cols[c2];
    ctab[i * 12 + 11] = nc;
    return;
  }
  const int idx = (bx - 8200) * 256 + t;    // 0..65535
  float s, c;
  sincosf(freqs[idx], &s, &c);
  rtab[idx] = make_float2(c, s);
}

// ---------------- GEMM common ----------------
__device__ inline void gld16(const bf16* g, bf16* l) {
  __builtin_amdgcn_global_load_lds((const __attribute__((address_space(1))) void*)g,
                                   (__attribute__((address_space(3))) void*)l, 16, 0, 0);
}

// ---- fused QKV GEMM: one block = 64(m) x 64(n) tile of q, k AND v (shared A staging).
// BK=64, XOR-swizzled LDS, 32 KB total. grid (64,16) = 1024 blocks at 4 blocks/CU:
// 16 waves/CU in ONE residency pass (R11's 128x64 tile gave only 2 blocks/CU -> stall-bound).
__global__ __launch_bounds__(256, 4) void qkv_gemm_kernel(
    const bf16* __restrict__ xb, const bf16* __restrict__ wqb, const bf16* __restrict__ wkb,
    const bf16* __restrict__ wvb, bf16* __restrict__ qb, bf16* __restrict__ kb, bf16* __restrict__ vb,
    const float2* __restrict__ rtab) {
  __shared__ __align__(16) bf16 As[64 * 64];        // 8 KB
  __shared__ __align__(16) bf16 Bs[3][64 * 64];     // 24 KB
  const bf16* Ws[3] = {wqb, wkb, wvb};
  bf16* Ds[3] = {qb, kb, vb};

  const int t = threadIdx.x;
  const int lane = t & 63;
  const int w = t >> 6;
  const int wm = (w >> 1) * 32;     // wave tile: 32(m) x 32(n)
  const int wn = (w & 1) * 32;
  const int m0 = blockIdx.x * 64;
  const int n0 = blockIdx.y * 64;
  const int l15 = lane & 15;
  const int kq = lane >> 4;         // 0..3

  f32x4 acc[3][2][2] = {};

  for (int k0 = 0; k0 < KD; k0 += 64) {
    // A: 64x64 = 512 slots of 16B; 2 per thread
#pragma unroll
    for (int n = 0; n < 2; ++n) {
      const int s = n * 256 + t;
      const int row = s >> 3;                  // 0..63
      const int ch = (s & 7) ^ (row & 7);      // XOR bank swizzle
      gld16(xb + (size_t)(m0 + row) * KD + k0 + ch * 8, As + s * 8);
    }
    // B_j: 64x64 = 512 slots each; 2 per thread per output
#pragma unroll
    for (int j = 0; j < 3; ++j)
#pragma unroll
      for (int n = 0; n < 2; ++n) {
        const int s = n * 256 + t;
        const int row = s >> 3;                // 0..63
        const int ch = (s & 7) ^ (row & 7);
        gld16(Ws[j] + (size_t)(n0 + row) * KD + k0 + ch * 8, &Bs[j][s * 8]);
      }
    __syncthreads();
#pragma unroll
    for (int ks = 0; ks < 2; ++ks) {
      const int cb = ks * 4 + kq;              // k-chunk 0..7
      bf16x8 af[2];
#pragma unroll
      for (int mt = 0; mt < 2; ++mt) {
        const int row = wm + mt * 16 + l15;
        af[mt] = *(const bf16x8*)(As + row * 64 + ((cb ^ (row & 7)) * 8));
      }
#pragma unroll
      for (int j = 0; j < 3; ++j) {
        bf16x8 bfr[2];
#pragma unroll
        for (int nt = 0; nt < 2; ++nt) {
          const int row = wn + nt * 16 + l15;
          bfr[nt] = *(const bf16x8*)(&Bs[j][row * 64 + ((cb ^ (row & 7)) * 8)]);
        }
#pragma unroll
        for (int mt = 0; mt < 2; ++mt)
#pragma unroll
          for (int nt = 0; nt < 2; ++nt)
            acc[j][mt][nt] = __builtin_amdgcn_mfma_f32_16x16x32_bf16(af[mt], bfr[nt], acc[j][mt][nt], 0, 0, 0);
      }
    }
    __syncthreads();
  }
  // C/D layout: col = lane&15, row = (lane>>4)*4 + reg   [verified m89]
  const int colb = n0 + wn + l15;
  const int rowb = m0 + wm + (lane >> 4) * 4;
  const int odd = l15 & 1;
#pragma unroll
  for (int j = 0; j < 3; ++j) {
    bf16* D = Ds[j];
    const bool dorope = (j < 2);
#pragma unroll
    for (int mt = 0; mt < 2; ++mt)
#pragma unroll
      for (int nt = 0; nt < 2; ++nt) {
        const int col = colb + nt * 16;
        const int jj = (col & 63) >> 1;
#pragma unroll
        for (int rr = 0; rr < 4; ++rr) {
          float val = acc[j][mt][nt][rr];
          float other = __shfl_xor(val, 1);    // partner column value
          if (!odd) {
            const int row = rowb + mt * 16 + rr;
            float lo, hi;
            if (dorope) {
              float2 cs = rtab[(row & (SEQ_L - 1)) * 32 + jj];
              lo = val * cs.x - other * cs.y;  // out_re
              hi = val * cs.y + other * cs.x;  // out_im
            } else { lo = val; hi = other; }
            bf16x2 p; p[0] = (bf16)lo; p[1] = (bf16)hi;
            *(bf16x2*)(D + (size_t)row * ND + col) = p;
          }
        }
      }
  }
}

// ---- out-projection GEMM: 64x128 tile, BK=64, swizzled; grid (64,8) = 512 blocks ----
// Blocks x==0 / x==32 first materialize row-0 attention output from (pm,pz,pv).
__global__ __launch_bounds__(256, 2) void out_gemm_kernel(
    bf16* __restrict__ ab, const bf16* __restrict__ wob, float* __restrict__ out,
    const float* __restrict__ pm, const float* __restrict__ pz, const float* __restrict__ pv) {
  const int t = threadIdx.x;
  const int m0 = blockIdx.x * 64;
  const int n0 = blockIdx.y * 128;

  if (blockIdx.x == 0 || blockIdx.x == 32) {
    const int b = blockIdx.x == 0 ? 0 : 1;
#pragma unroll
    for (int e = t; e < DM; e += 256) {
      const int h = e >> 6, d = e & 63;
      const int base = b * 128 + h * 8;
      float M = -1e30f;
#pragma unroll
      for (int c = 0; c < 8; ++c) M = fmaxf(M, pm[base + c]);
      float Z = 0.f, od = 0.f;
#pragma unroll
      for (int c = 0; c < 8; ++c) {
        float sc = __expf(pm[base + c] - M);
        Z += pz[base + c] * sc;
        od += pv[(base + c) * 64 + d] * sc;
      }
      ab[(size_t)b * SEQ_L * DM + e] = (bf16)(od / Z);
    }
    __syncthreads();   // drain stores before staging reads the same row
  }

  __shared__ __align__(16) bf16 As[64 * 64];    // 8 KB
  __shared__ __align__(16) bf16 Bs[128 * 64];   // 16 KB
  const int lane = t & 63;
  const int wave = t >> 6;
  const int wm = (wave >> 1) * 32;
  const int wn = (wave & 1) * 64;
  const int l15 = lane & 15;
  const int kq = lane >> 4;

  f32x4 acc[2][4] = {};

  for (int k0 = 0; k0 < KD; k0 += 64) {
#pragma unroll
    for (int n = 0; n < 2; ++n) {
      const int s = n * 256 + t;               // 512 slots for As
      const int row = s >> 3;                  // 0..63
      const int ch = (s & 7) ^ (row & 7);
      gld16(ab + (size_t)(m0 + row) * KD + k0 + ch * 8, As + s * 8);
    }
#pragma unroll
    for (int n = 0; n < 4; ++n) {
      const int s = n * 256 + t;               // 1024 slots for Bs
      const int row = s >> 3;                  // 0..127
      const int ch = (s & 7) ^ (row & 7);
      gld16(wob + (size_t)(n0 + row) * KD + k0 + ch * 8, Bs + s * 8);
    }
    __syncthreads();
#pragma unroll
    for (int ks = 0; ks < 2; ++ks) {
      const int cb = ks * 4 + kq;
      bf16x8 af[2], bfr[4];
#pragma unroll
      for (int mt = 0; mt < 2; ++mt) {
        const int row = wm + mt * 16 + l15;
        af[mt] = *(const bf16x8*)(As + row * 64 + ((cb ^ (row & 7)) * 8));
      }
#pragma unroll
      for (int nt = 0; nt < 4; ++nt) {
        const int row = wn + nt * 16 + l15;
        bfr[nt] = *(const bf16x8*)(Bs + row * 64 + ((cb ^ (row & 7)) * 8));
      }
#pragma unroll
      for (int mt = 0; mt < 2; ++mt)
#pragma unroll
        for (int nt = 0; nt < 4; ++nt)
          acc[mt][nt] = __builtin_amdgcn_mfma_f32_16x16x32_bf16(af[mt], bfr[nt], acc[mt][nt], 0, 0, 0);
    }
    __syncthreads();
  }
  const int colb = n0 + wn + l15;
  const int rowb = m0 + wm + (lane >> 4) * 4;
#pragma unroll
  for (int mt = 0; mt < 2; ++mt)
#pragma unroll
    for (int nt = 0; nt < 4; ++nt)
#pragma unroll
      for (int rr = 0; rr < 4; ++rr)
        out[(size_t)(rowb + mt * 16 + rr) * ND + colb + nt * 16] = acc[mt][nt][rr];
}

// ---------------- attention ----------------
// grid (1280, 1), 256 threads.
//  bx < 256  : row-0 partials per (b, h, 256-col chunk) -> pm/pz/pv (dispatched FIRST: no tail).
//  bx >= 256 : sparse rows; wave handles one row i for ALL 16 heads (2KB wave-loads).
//  v2 (T14-lite): K quads prefetched up-front; V loads issued AFTER the QK dots so the
//  allocator reuses K's ~88 VGPRs for V (peak ~150 vs ~230) -> __launch_bounds__(256,3)
//  = 12 waves/CU (was 8). V latency hides under the softmax VALU. Values identical.
__global__ __launch_bounds__(256, 3) void attn_kernel(const bf16* __restrict__ q, const bf16* __restrict__ k,
                                                      const bf16* __restrict__ v, bf16* __restrict__ o,
                                                      const int* __restrict__ ctab,
                                                      float* __restrict__ pm, float* __restrict__ pz,
                                                      float* __restrict__ pv) {
  const int t = threadIdx.x;
  const int lane = t & 63;
  const int w = t >> 6;

  __shared__ float sbuf[256];
  __shared__ float redm[4], redz[4];
  __shared__ float part[4][64];

  if (blockIdx.x >= 256) {
    const int sbx = blockIdx.x - 256;               // 0..1023
    const int b = sbx >> 9;
    const int tt = sbx & 511;
    const int tile = ((tt & 7) << 6) + (tt >> 3);   // XCD swizzle
    const int i = tile * 4 + 1 + w;
    if (i >= SEQ_L) return;   // wave-uniform
    const size_t bb = (size_t)b * SEQ_L * DM;
    const int eo = lane * 16;

    const bf16* qrow = q + bb + (size_t)i * DM + eo;
    bf16x8 qv0 = *(const bf16x8*)(qrow);
    bf16x8 qv1 = *(const bf16x8*)(qrow + 8);

    const int4* cp = (const int4*)(ctab + i * 12);
    int4 ca = cp[0], cb = cp[1], cc = cp[2];
    int cols[11] = {ca.x, ca.y, ca.z, ca.w, cb.x, cb.y, cb.z, cb.w, cc.x, cc.y, cc.z};

    // prefetch all K rows into registers (22 independent 16B loads in flight)
    bf16x8 kv[11][2];
#pragma unroll
    for (int c = 0; c < 11; ++c) {
      int cj = cols[c] < 0 ? 0 : cols[c];
      const bf16* krow = k + bb + (size_t)cj * DM + eo;
      kv[c][0] = *(const bf16x8*)(krow);
      kv[c][1] = *(const bf16x8*)(krow + 8);
    }

    float sv[11];
#pragma unroll
    for (int c = 0; c < 11; ++c) {
      float acc = 0.f;
#pragma unroll
      for (int e = 0; e < 8; ++e)
        acc += (float)qv0[e] * (float)kv[c][0][e] + (float)qv1[e] * (float)kv[c][1][e];
      sv[c] = acc;
    }

    // issue V loads now: K registers are dead (reused for V); softmax below covers latency
    bf16x8 vv[11][2];
#pragma unroll
    for (int c = 0; c < 11; ++c) {
      int cj = cols[c] < 0 ? 0 : cols[c];
      const bf16* vrow = v + bb + (size_t)cj * DM + eo;
      vv[c][0] = *(const bf16x8*)(vrow);
      vv[c][1] = *(const bf16x8*)(vrow + 8);
    }

#pragma unroll
    for (int c = 0; c < 11; ++c) {
      sv[c] += __shfl_xor(sv[c], 1);
      sv[c] += __shfl_xor(sv[c], 2);
      sv[c] = cols[c] < 0 ? -1e30f : sv[c] * 0.125f;
    }
    float m = -1e30f;
#pragma unroll
    for (int c = 0; c < 11; ++c) m = fmaxf(m, sv[c]);
    float z = 0.f;
#pragma unroll
    for (int c = 0; c < 11; ++c) { sv[c] = __expf(sv[c] - m); z += sv[c]; }
    const float inv = 1.f / z;

    float oa[16] = {};
#pragma unroll
    for (int c = 0; c < 11; ++c) {
#pragma unroll
      for (int e = 0; e < 8; ++e) {
        oa[e]     += sv[c] * (float)vv[c][0][e];
        oa[8 + e] += sv[c] * (float)vv[c][1][e];
      }
    }
    bf16x8 ov0, ov1;
#pragma unroll
    for (int e = 0; e < 8; ++e) {
      ov0[e] = (bf16)(oa[e] * inv);
      ov1[e] = (bf16)(oa[8 + e] * inv);
    }
    bf16* orow = o + bb + (size_t)i * DM + eo;
    *(bf16x8*)(orow) = ov0;
    *(bf16x8*)(orow + 8) = ov1;
    return;
  }

  // ---- row-0 partial: (b, h, chunk of 256 cols) ----
  const int idx = blockIdx.x;           // 0..255
  const int b = idx >> 7;
  const int rem = idx & 127;
  const int h = rem >> 3;
  const int c = rem & 7;
  const size_t hb = (size_t)b * SEQ_L * DM + (size_t)h * HD;
  const int j = c * 256 + t;

  bf16x8 qv8[8];
#pragma unroll
  for (int cc = 0; cc < 8; ++cc) qv8[cc] = *(const bf16x8*)(q + hb + cc * 8);

  float acc = 0.f;
#pragma unroll
  for (int cc = 0; cc < 8; ++cc) {
    bf16x8 kv = *(const bf16x8*)(k + hb + (size_t)j * DM + cc * 8);
#pragma unroll
    for (int e = 0; e < 8; ++e) acc += (float)qv8[cc][e] * (float)kv[e];
  }
  float s = acc * 0.125f;
  float mloc = s;
#pragma unroll
  for (int off = 32; off > 0; off >>= 1) mloc = fmaxf(mloc, __shfl_xor(mloc, off));
  if (lane == 0) redm[w] = mloc;
  __syncthreads();
  const float m = fmaxf(fmaxf(redm[0], redm[1]), fmaxf(redm[2], redm[3]));

  float e = __expf(s - m);
  sbuf[t] = e;
  float zloc = e;
#pragma unroll
  for (int off = 32; off > 0; off >>= 1) zloc += __shfl_xor(zloc, off);
  if (lane == 0) redz[w] = zloc;
  __syncthreads();
  const float zc = redz[0] + redz[1] + redz[2] + redz[3];

  float oa = 0.f;
  for (int jj = w; jj < 256; jj += 4)
    oa += sbuf[jj] * (float)v[hb + (size_t)(c * 256 + jj) * DM + lane];
  part[w][lane] = oa;
  __syncthreads();
  if (t < 64) pv[idx * 64 + t] = part[0][t] + part[1][t] + part[2][t] + part[3][t];
  if (t == 0) { pm[idx] = m; pz[idx] = zc; }
}

// ---------------- launch ----------------
extern "C" void kernel_launch(void* const* d_in, const int* in_sizes, int n_in,
                              void* d_out, int out_size, void* d_ws, size_t ws_size,
                              hipStream_t stream) {
  const float* x     = (const float*)d_in[0];
  const float* freqs = (const float*)d_in[1];
  const float* wq    = (const float*)d_in[2];
  const float* wk    = (const float*)d_in[3];
  const float* wv    = (const float*)d_in[4];
  const float* wo    = (const float*)d_in[5];
  float* out = (float*)d_out;

  char* ws = (char*)d_ws;
  bf16* xb  = (bf16*)(ws + 0);          // 8 MiB
  bf16* wqb = (bf16*)(ws + 8388608);    // 2 MiB each
  bf16* wkb = (bf16*)(ws + 10485760);
  bf16* wvb = (bf16*)(ws + 12582912);
  bf16* wob = (bf16*)(ws + 14680064);
  bf16* qb  = (bf16*)(ws + 16777216);   // 8 MiB [B,L,H,HD]
  bf16* kb  = (bf16*)(ws + 25165824);
  bf16* vb  = (bf16*)(ws + 33554432);
  bf16* ab  = (bf16*)(ws + 41943040);   // 8 MiB; end 48 MiB
  int*    ctab = (int*)(ws + 50331648); // 96 KB
  float*  pm   = (float*)(ws + 50462720);
  float*  pz   = (float*)(ws + 50463744);
  float*  pv   = (float*)(ws + 50464768);   // 64 KB
  float2* rtab = (float2*)(ws + 50593792);  // 512 KB rope cos/sin table
  (void)ws_size;

  prep_kernel<<<8456, 256, 0, stream>>>(x, wq, wk, wv, wo, freqs, xb, wqb, wkb, wvb, wob, ctab, rtab);
  qkv_gemm_kernel<<<dim3(64, 16), 256, 0, stream>>>(xb, wqb, wkb, wvb, qb, kb, vb, rtab);
  attn_kernel<<<dim3(1280, 1), 256, 0, stream>>>(qb, kb, vb, ab, ctab, pm, pz, pv);
  out_gemm_kernel<<<dim3(64, 8), 256, 0, stream>>>(ab, wob, out, pm, pz, pv);
}